// Round 8
// baseline (392.704 us; speedup 1.0000x reference)
//
#include <hip/hip_runtime.h>

#define HH 384
#define WW 384
#define BB 2

typedef unsigned short ushort_t;
typedef short  s16x8 __attribute__((ext_vector_type(8)));
typedef float  f32x4 __attribute__((ext_vector_type(4)));
typedef int    i32x4 __attribute__((ext_vector_type(4)));
typedef int    i32x2 __attribute__((ext_vector_type(2)));

union V16 { i32x4 i4; s16x8 v; ushort_t h[8]; };
union V8  { i32x2 i2; ushort_t h[4]; };

__device__ __forceinline__ ushort_t f2b(float f) {           // RNE fp32->bf16
    unsigned u = __builtin_bit_cast(unsigned, f);
    u += 0x7fffu + ((u >> 16) & 1u);
    return (ushort_t)(u >> 16);
}
__device__ __forceinline__ float b2f(ushort_t h) {
    return __builtin_bit_cast(float, ((unsigned)h) << 16);
}

// ---------------------------------------------------------------------------
// Weight repack. s-major, t = ky*3+kx consecutive -> (s,ky) groups of 3 kx
// units are contiguous (768 slots for main convs, and (s,t)-units of 192
// slots for w_out). Main convs j=0..5: [s(2)][t(9)][mt(4)][lane(64)][i(8)],
// 36864 each. w_out: [s(2)][t(9)][mt(3)][lane][i]: 27648. w_first: 2048.
// ---------------------------------------------------------------------------
struct WSrc { const float* p[8]; };

__global__ __launch_bounds__(256)
void repack_k(WSrc ws, ushort_t* __restrict__ Wd)
{
    const int idx = blockIdx.x * 256 + threadIdx.x;
    float val = 0.f;
    if (idx < 221184) {
        const int j = idx / 36864, rem = idx - j * 36864;
        const int i = rem & 7, lane = (rem >> 3) & 63;
        const int f = rem >> 9;                  // (s*9+t)*4+mt
        const int mt = f & 3, st = f >> 2;
        const int t = st % 9, s = st / 9;
        const int co = mt * 16 + (lane & 15);
        const int ci = s * 32 + (lane >> 4) * 8 + i;
        val = ws.p[j][((size_t)(co * 64 + ci)) * 9 + t];
    } else if (idx < 248832) {
        const int rem = idx - 221184;
        const int i = rem & 7, lane = (rem >> 3) & 63;
        const int f = rem >> 9;                  // (s*9+t)*3+mt
        const int mt = f % 3, st = f / 3;
        const int t = st % 9, s = st / 9;
        const int co = mt * 16 + (lane & 15);
        const int ci = s * 32 + (lane >> 4) * 8 + i;
        val = (co < 35) ? ws.p[6][((size_t)(co * 64 + ci)) * 9 + t] : 0.f;
    } else {
        const int rem = idx - 248832;            // < 2048
        const int i = rem & 7, lane = (rem >> 3) & 63;
        const int mt = rem >> 9;
        const int co = mt * 16 + (lane & 15);
        const int k = (lane >> 4) * 8 + i;
        if (k < 18) {
            const int ch = (k >= 9) ? 1 : 0;
            const int t = k - ch * 9;
            val = ws.p[7][((size_t)(co * 2 + ch)) * 9 + t];
        }
    }
    if (idx < 250880) Wd[idx] = f2b(val);
}

// ---------------------------------------------------------------------------
// Main conv: implicit GEMM, all-LDS inner loop, STREAMED weight groups.
// LDS: act 41472 B + wgt group buffer 12288 B (one (s,ky) group = 3 kx units
// x 4 mt x 64 lanes x 16 B) = 53760 B -> 3 blocks/CU (12 waves).
// Next group register-prefetched (3 x i32x4/thread) during current compute.
// (256,3): VGPR cap 170; est. live ~112 (acc 64 + bf 16 + pw 12 + addr).
// R3 lesson: never cap below the live set — spill goes to HBM scratch.
// ---------------------------------------------------------------------------
template<bool RELU, bool RES>
__global__ __launch_bounds__(256, 3)
void conv_mfma(const ushort_t* __restrict__ in, const ushort_t* __restrict__ wp,
               const float* __restrict__ bias, const ushort_t* __restrict__ res,
               ushort_t* __restrict__ out)
{
    __shared__ __align__(16) char smem[41472 + 12288];
    i32x4* s4 = (i32x4*)smem;                    // act: [(r*8+oct)*18 + x]
    i32x4* sw = (i32x4*)(smem + 41472);          // wgt group: [kx(3)][mt(4)][lane]

    const int tid = threadIdx.x;
    const int x0 = blockIdx.x * 16, y0 = blockIdx.y * 16, b = blockIdx.z;
    const int lane = tid & 63, w4 = (tid >> 6) * 4;
    const int n = lane & 15, q = lane >> 4;

    // ---- batched staging: act (11 loads) + wgt group0 (3 loads) ----
    {
        i32x4 ta[11];
#pragma unroll
        for (int k = 0; k < 11; ++k) {
            const int idx = tid + k * 256;
            ta[k] = 0;
            if (idx < 2592) {
                const int oct = idx & 7, p = idx >> 3;
                const int r = p / 18, xx = p - r * 18;
                const int gy = y0 - 1 + r, gx = x0 - 1 + xx;
                if ((unsigned)gy < HH && (unsigned)gx < WW)
                    ta[k] = *(const i32x4*)(in +
                        ((size_t)((b * HH + gy) * WW + gx)) * 64 + oct * 8);
            }
        }
        i32x4 tw[3];
#pragma unroll
        for (int k = 0; k < 3; ++k)
            tw[k] = *(const i32x4*)(wp + (size_t)(tid + k * 256) * 8);
#pragma unroll
        for (int k = 0; k < 11; ++k) {
            const int idx = tid + k * 256;
            if (idx < 2592) {
                const int oct = idx & 7, p = idx >> 3;
                const int r = p / 18, xx = p - r * 18;
                s4[(r * 8 + oct) * 18 + xx] = ta[k];
            }
        }
#pragma unroll
        for (int k = 0; k < 3; ++k)
            sw[tid + k * 256] = tw[k];
    }
    __syncthreads();

    f32x4 acc[4][4];
#pragma unroll
    for (int i = 0; i < 4; ++i)
#pragma unroll
        for (int j = 0; j < 4; ++j) acc[i][j] = 0.f;

    // prefetch group 1 (slots 768..1535)
    i32x4 pw[3];
#pragma unroll
    for (int k = 0; k < 3; ++k)
        pw[k] = *(const i32x4*)(wp + (size_t)(768 + tid + k * 256) * 8);

    // ---- 6 groups: grp = s*3 + ky ----
#pragma unroll
    for (int grp = 0; grp < 6; ++grp) {
        const int s = grp / 3, ky = grp - s * 3;
#pragma unroll
        for (int kx = 0; kx < 3; ++kx) {
            V16 bf[4];
#pragma unroll
            for (int nt = 0; nt < 4; ++nt)
                bf[nt].i4 = s4[((w4 + nt + ky) * 8 + s * 4 + q) * 18 + (n + kx)];
#pragma unroll
            for (int mt = 0; mt < 4; ++mt) {
                V16 af; af.i4 = sw[(kx * 4 + mt) * 64 + lane];
#pragma unroll
                for (int nt = 0; nt < 4; ++nt)
                    acc[nt][mt] = __builtin_amdgcn_mfma_f32_16x16x32_bf16(
                        af.v, bf[nt].v, acc[nt][mt], 0, 0, 0);
            }
        }
        if (grp < 5) {
            __syncthreads();                     // all reads of current group done
#pragma unroll
            for (int k = 0; k < 3; ++k)
                sw[tid + k * 256] = pw[k];
            if (grp < 4) {
#pragma unroll
                for (int k = 0; k < 3; ++k)
                    pw[k] = *(const i32x4*)(wp +
                        (size_t)(768 * (grp + 2) + tid + k * 256) * 8);
            }
            __syncthreads();                     // writes visible
        }
    }

    // ---- transpose epilogue (aliases act region, 32 KB < 41.5 KB) ----
    __syncthreads();
#pragma unroll
    for (int nt = 0; nt < 4; ++nt) {
        const int row = w4 + nt;
#pragma unroll
        for (int mt = 0; mt < 4; ++mt) {
            const int co0 = mt * 16 + q * 4;
            const float4 bv = *(const float4*)(bias + co0);
            float vv[4] = {acc[nt][mt][0] + bv.x, acc[nt][mt][1] + bv.y,
                           acc[nt][mt][2] + bv.z, acc[nt][mt][3] + bv.w};
            V8 ov;
#pragma unroll
            for (int r = 0; r < 4; ++r)
                ov.h[r] = f2b(RELU ? fmaxf(vv[r], 0.f) : vv[r]);
            const int c = 2 * mt + (q >> 1);
            const int cpr = c ^ (n & 7);
            *(i32x2*)(smem + row * 2048 + n * 128 + cpr * 16 + (q & 1) * 8) = ov.i2;
        }
    }
    __syncthreads();
    // readback: 64 lanes x 16B = 1 KB contiguous per wave instruction;
    // residual added here (same coalesced pattern).
#pragma unroll
    for (int r0 = 0; r0 < 4; ++r0) {
        const int row = w4 + r0, y = y0 + row;
#pragma unroll
        for (int j = 0; j < 2; ++j) {
            const int px = (lane >> 3) + 8 * j;
            const int clin = lane & 7;
            const int cpr = clin ^ (px & 7);
            V16 v;
            v.i4 = *(const i32x4*)(smem + row * 2048 + px * 128 + cpr * 16);
            const size_t goff = ((size_t)((b * HH + y) * WW + x0 + px)) * 64
                                + clin * 8;
            if (RES) {
                V16 rv;
                rv.i4 = *(const i32x4*)(res + goff);
#pragma unroll
                for (int e = 0; e < 8; ++e)
                    v.h[e] = f2b(b2f(v.h[e]) + b2f(rv.h[e]));
            }
            *(i32x4*)(out + goff) = v.i4;
        }
    }
}

// ---------------------------------------------------------------------------
// First conv: CI=2 fp32 NCHW, K=18 padded to 32, transpose epilogue.
// ---------------------------------------------------------------------------
__global__ __launch_bounds__(256, 4)
void conv_first(const float* __restrict__ in, const ushort_t* __restrict__ wp,
                const float* __restrict__ bias, ushort_t* __restrict__ out)
{
    __shared__ float s_raw[2][18][20];
    __shared__ __align__(16) char epi[32768];
    const int tid = threadIdx.x;
    const int x0 = blockIdx.x * 16, y0 = blockIdx.y * 16, b = blockIdx.z;
    {
        float tmp[3];
#pragma unroll
        for (int k = 0; k < 3; ++k) {
            const int idx = tid + k * 256;
            tmp[k] = 0.f;
            if (idx < 648) {
                const int ch = idx / 324, rem = idx - ch * 324;
                const int r = rem / 18, x = rem - r * 18;
                const int gy = y0 - 1 + r, gx = x0 - 1 + x;
                if ((unsigned)gy < HH && (unsigned)gx < WW)
                    tmp[k] = in[((size_t)((b * 2 + ch) * HH + gy)) * WW + gx];
            }
        }
#pragma unroll
        for (int k = 0; k < 3; ++k) {
            const int idx = tid + k * 256;
            if (idx < 648) {
                const int ch = idx / 324, rem = idx - ch * 324;
                const int r = rem / 18, x = rem - r * 18;
                s_raw[ch][r][x] = tmp[k];
            }
        }
    }
    __syncthreads();

    const int lane = tid & 63, w4 = (tid >> 6) * 4;
    const int n = lane & 15, q = lane >> 4;

    V16 af[4];
#pragma unroll
    for (int mt = 0; mt < 4; ++mt)
        af[mt].i4 = *(const i32x4*)(wp + ((size_t)(mt * 64 + lane)) * 8);

    f32x4 acc[4][4];
#pragma unroll
    for (int i = 0; i < 4; ++i)
#pragma unroll
        for (int j = 0; j < 4; ++j) acc[i][j] = 0.f;

#pragma unroll
    for (int nt = 0; nt < 4; ++nt) {
        const int r = w4 + nt;
        V16 bf;
#pragma unroll
        for (int i = 0; i < 8; ++i) {
            const int k = q * 8 + i;
            float v = 0.f;
            if (k < 18) {
                const int ch = (k >= 9) ? 1 : 0;
                const int t = k - ch * 9;
                const int ky = t / 3, kx = t - ky * 3;
                v = s_raw[ch][r + ky][n + kx];
            }
            bf.h[i] = f2b(v);
        }
#pragma unroll
        for (int mt = 0; mt < 4; ++mt)
            acc[nt][mt] = __builtin_amdgcn_mfma_f32_16x16x32_bf16(
                af[mt].v, bf.v, acc[nt][mt], 0, 0, 0);
    }

#pragma unroll
    for (int nt = 0; nt < 4; ++nt) {
        const int row = w4 + nt;
#pragma unroll
        for (int mt = 0; mt < 4; ++mt) {
            const int co0 = mt * 16 + q * 4;
            const float4 bv = *(const float4*)(bias + co0);
            V8 ov;
            ov.h[0] = f2b(acc[nt][mt][0] + bv.x);
            ov.h[1] = f2b(acc[nt][mt][1] + bv.y);
            ov.h[2] = f2b(acc[nt][mt][2] + bv.z);
            ov.h[3] = f2b(acc[nt][mt][3] + bv.w);
            const int c = 2 * mt + (q >> 1);
            const int cpr = c ^ (n & 7);
            *(i32x2*)(epi + row * 2048 + n * 128 + cpr * 16 + (q & 1) * 8) = ov.i2;
        }
    }
    __syncthreads();
#pragma unroll
    for (int r0 = 0; r0 < 4; ++r0) {
        const int row = w4 + r0, y = y0 + row;
#pragma unroll
        for (int j = 0; j < 2; ++j) {
            const int px = (lane >> 3) + 8 * j;
            const int clin = lane & 7;
            const int cpr = clin ^ (px & 7);
            i32x4 v = *(const i32x4*)(epi + row * 2048 + px * 128 + cpr * 16);
            *(i32x4*)(out + ((size_t)((b * HH + y) * WW + x0 + px)) * 64
                          + clin * 8) = v;
        }
    }
}

// ---------------------------------------------------------------------------
// KPN: array-free, d2-grouped, compile-time recursion (R5 — fixed the scratch
// spill). No max-subtraction: softmax ratio unchanged, |core| logits are small.
// ---------------------------------------------------------------------------
constexpr int isq_(int v) { int r = 0; while ((r + 1) * (r + 1) <= v) ++r; return r; }
constexpr double csqrt_(int x) {
    double g = x ? (double)x : 0.0;
    if (x) for (int i = 0; i < 80; ++i) g = 0.5 * (g + (double)x / g);
    return g;
}
constexpr int tapm_(int W, int d2) {
    const int R = W - 1; int c = 0;
    for (int di = -R; di <= R; ++di)
        for (int dj = -R; dj <= R; ++dj)
            if (di * di + dj * dj == d2) ++c;
    return c;
}
constexpr int nout_(int W) {
    const int R = W - 1; int c = 0;
    for (int di = -R; di <= R; ++di)
        for (int dj = -R; dj <= R; ++dj)
            if (di * di + dj * dj > R * R) ++c;
    return c;
}

template<int W, int D2, int DI>
struct DiSum {
    static constexpr int R = W - 1;
    static __device__ __forceinline__ float run(const float* s_f, int base) {
        float s = 0.f;
        constexpr int rem = D2 - DI * DI;
        if constexpr (rem >= 0) {
            constexpr int sj = isq_(rem >= 0 ? rem : 0);
            if constexpr (sj * sj == rem) {
                s += s_f[base + DI * 48 + sj];
                if constexpr (sj > 0) s += s_f[base + DI * 48 - sj];
            }
        }
        if constexpr (DI < R) s += DiSum<W, D2, DI + 1>::run(s_f, base);
        return s;
    }
};

template<int W, int OFF, int D2>
struct D2Loop {
    static __device__ __forceinline__ void run(const float* cv, const float* s_f,
                                               int base, float& num, float& den) {
        constexpr int m = tapm_(W, D2);
        if constexpr (m > 0) {
            constexpr int lo = isq_(D2);
            float v;
            if constexpr (lo * lo == D2) {
                v = cv[OFF + lo];
            } else {
                constexpr float fr = (float)(csqrt_(D2) - (double)lo);
                v = __builtin_fmaf(fr, cv[OFF + lo + 1] - cv[OFF + lo], cv[OFF + lo]);
            }
            const float e = __expf(v);
            const float S = DiSum<W, D2, -(W - 1)>::run(s_f, base);
            num = __builtin_fmaf(e, S, num);
            den = __builtin_fmaf((float)m, e, den);
        }
        if constexpr (D2 > 0)
            D2Loop<W, OFF, D2 - 1>::run(cv, s_f, base, num, den);
    }
};

template<int W, int OFF>
__device__ __forceinline__ float kpn_section(const float* cv, const float* s_f,
                                             int base)
{
    constexpr int R = W - 1, R2 = R * R;
    float sout = 0.f;                            // outside taps: e = exp(0) = 1
#pragma unroll
    for (int di = -R; di <= R; ++di)
#pragma unroll
        for (int dj = -R; dj <= R; ++dj)
            if (di * di + dj * dj > R2)
                sout += s_f[base + di * 48 + dj];
    float num = sout, den = (float)nout_(W);
    D2Loop<W, OFF, R2>::run(cv, s_f, base, num, den);
    return num / den;
}

// ---------------------------------------------------------------------------
// Fused out-conv (64->35, COT=3) + KPN, streamed weight groups (2 t-units =
// 384 slots = 6144 B). LDS: stage 41472 (aliased by core px-major 256x37 fp32)
// + frames 5760 + wgt 6144 = 53376 B -> 3 blocks/CU.
// ---------------------------------------------------------------------------
__global__ __launch_bounds__(256, 3)
void conv_kpn(const ushort_t* __restrict__ in, const ushort_t* __restrict__ wp,
              const float* __restrict__ bias, const float* __restrict__ frames,
              float* __restrict__ out)
{
    __shared__ __align__(16) char smem[41472 + 5760 + 6144];
    i32x4* s4 = (i32x4*)smem;                    // stage [(r*8+oct)*18+x]
    float* s_core = (float*)smem;                // [px 256][ch 37]
    float* s_f = (float*)(smem + 41472);         // frames 30x48
    i32x4* sw = (i32x4*)(smem + 41472 + 5760);   // wgt group: 384 slots

    const int tid = threadIdx.x;
    const int x0 = blockIdx.x * 16, y0 = blockIdx.y * 16, b = blockIdx.z;

    {
        i32x4 ta[11];
#pragma unroll
        for (int k = 0; k < 11; ++k) {
            const int idx = tid + k * 256;
            ta[k] = 0;
            if (idx < 2592) {
                const int oct = idx & 7, p = idx >> 3;
                const int r = p / 18, xx = p - r * 18;
                const int gy = y0 - 1 + r, gx = x0 - 1 + xx;
                if ((unsigned)gy < HH && (unsigned)gx < WW)
                    ta[k] = *(const i32x4*)(in +
                        ((size_t)((b * HH + gy) * WW + gx)) * 64 + oct * 8);
            }
        }
        float ff[4];
#pragma unroll
        for (int k = 0; k < 4; ++k) {
            const int idx = tid + k * 256;
            ff[k] = 0.f;
            if (idx < 900) {
                const int r = idx / 30, c = idx - r * 30;
                const int y = y0 - 7 + r, x = x0 - 7 + c;
                if ((unsigned)y < HH && (unsigned)x < WW)
                    ff[k] = frames[((size_t)b * HH + y) * WW + x];
            }
        }
        i32x4 tw[2];
#pragma unroll
        for (int k = 0; k < 2; ++k) {
            const int idx = tid + k * 256;
            tw[k] = 0;
            if (idx < 384)
                tw[k] = *(const i32x4*)(wp + (size_t)idx * 8);
        }
#pragma unroll
        for (int k = 0; k < 11; ++k) {
            const int idx = tid + k * 256;
            if (idx < 2592) {
                const int oct = idx & 7, p = idx >> 3;
                const int r = p / 18, xx = p - r * 18;
                s4[(r * 8 + oct) * 18 + xx] = ta[k];
            }
        }
#pragma unroll
        for (int k = 0; k < 4; ++k) {
            const int idx = tid + k * 256;
            if (idx < 900) {
                const int r = idx / 30, c = idx - r * 30;
                s_f[r * 48 + c] = ff[k];
            }
        }
#pragma unroll
        for (int k = 0; k < 2; ++k) {
            const int idx = tid + k * 256;
            if (idx < 384) sw[idx] = tw[k];
        }
    }
    __syncthreads();

    const int lane = tid & 63, w4 = (tid >> 6) * 4;
    const int n = lane & 15, q = lane >> 4;

    f32x4 acc[4][3];
#pragma unroll
    for (int i = 0; i < 4; ++i)
#pragma unroll
        for (int j = 0; j < 3; ++j) acc[i][j] = 0.f;

    // prefetch group 1 (slots 384..767)
    i32x4 pw[2];
#pragma unroll
    for (int k = 0; k < 2; ++k) {
        const int idx = tid + k * 256;
        pw[k] = 0;
        if (idx < 384)
            pw[k] = *(const i32x4*)(wp + (size_t)(384 + idx) * 8);
    }

    // ---- 9 groups of 2 t-units (u = s*9 + t) ----
#pragma unroll
    for (int grp = 0; grp < 9; ++grp) {
#pragma unroll
        for (int uu = 0; uu < 2; ++uu) {
            const int u = grp * 2 + uu;
            const int s = u / 9, t = u - s * 9;
            const int ky = t / 3, kx = t - ky * 3;
            V16 bf[4];
#pragma unroll
            for (int nt = 0; nt < 4; ++nt)
                bf[nt].i4 = s4[((w4 + nt + ky) * 8 + s * 4 + q) * 18 + (n + kx)];
#pragma unroll
            for (int mt = 0; mt < 3; ++mt) {
                V16 af; af.i4 = sw[uu * 192 + mt * 64 + lane];
#pragma unroll
                for (int nt = 0; nt < 4; ++nt)
                    acc[nt][mt] = __builtin_amdgcn_mfma_f32_16x16x32_bf16(
                        af.v, bf[nt].v, acc[nt][mt], 0, 0, 0);
            }
        }
        if (grp < 8) {
            __syncthreads();
#pragma unroll
            for (int k = 0; k < 2; ++k) {
                const int idx = tid + k * 256;
                if (idx < 384) sw[idx] = pw[k];
            }
            if (grp < 7) {
#pragma unroll
                for (int k = 0; k < 2; ++k) {
                    const int idx = tid + k * 256;
                    pw[k] = 0;
                    if (idx < 384)
                        pw[k] = *(const i32x4*)(wp +
                            (size_t)(384 * (grp + 2) + idx) * 8);
                }
            }
            __syncthreads();
        }
    }

    __syncthreads();                             // stage reads done; write core
#pragma unroll
    for (int nt = 0; nt < 4; ++nt) {
        const int px = (w4 + nt) * 16 + n;
#pragma unroll
        for (int mt = 0; mt < 3; ++mt) {
#pragma unroll
            for (int r = 0; r < 4; ++r) {
                const int ch = mt * 16 + q * 4 + r;
                if (ch < 35)
                    s_core[px * 37 + ch] = fabsf(acc[nt][mt][r] + bias[ch]);
            }
        }
    }
    __syncthreads();

    const int ty = tid >> 4, tx = tid & 15;
    const int base = (ty + 7) * 48 + (tx + 7);
    const float* cv = s_core + tid * 37;
    float pred = 0.f;
    pred += kpn_section<2, 0>(cv, s_f, base);
    pred += kpn_section<3, 2>(cv, s_f, base);
    pred += kpn_section<4, 5>(cv, s_f, base);
    pred += kpn_section<5, 9>(cv, s_f, base);
    pred += kpn_section<6, 14>(cv, s_f, base);
    pred += kpn_section<7, 20>(cv, s_f, base);
    pred += kpn_section<8, 27>(cv, s_f, base);
    out[((size_t)b * HH + y0 + ty) * WW + x0 + tx] = pred;
}

// ---------------------------------------------------------------------------
extern "C" void kernel_launch(void* const* d_in, const int* in_sizes, int n_in,
                              void* d_out, int out_size, void* d_ws, size_t ws_size,
                              hipStream_t stream)
{
    const float* est     = (const float*)d_in[0];
    const float* data    = (const float*)d_in[1];
    const float* w_first = (const float*)d_in[2];
    const float* b_first = (const float*)d_in[3];
    const float* w1a = (const float*)d_in[4];
    const float* b1a = (const float*)d_in[5];
    const float* w1b = (const float*)d_in[6];
    const float* b1b = (const float*)d_in[7];
    const float* w2a = (const float*)d_in[8];
    const float* b2a = (const float*)d_in[9];
    const float* w2b = (const float*)d_in[10];
    const float* b2b = (const float*)d_in[11];
    const float* w3a = (const float*)d_in[12];
    const float* b3a = (const float*)d_in[13];
    const float* w3b = (const float*)d_in[14];
    const float* b3b = (const float*)d_in[15];
    const float* w_out = (const float*)d_in[16];
    const float* b_out = (const float*)d_in[17];

    ushort_t* X  = (ushort_t*)d_ws;                         // NHWC bf16 (B,H,W,64)
    ushort_t* T  = X + (size_t)BB * HH * WW * 64;
    ushort_t* Wd = T + (size_t)BB * HH * WW * 64;           // repacked weights

    WSrc wsrc;
    wsrc.p[0] = w1a; wsrc.p[1] = w1b; wsrc.p[2] = w2a; wsrc.p[3] = w2b;
    wsrc.p[4] = w3a; wsrc.p[5] = w3b; wsrc.p[6] = w_out; wsrc.p[7] = w_first;

    dim3 blk(256), g(WW / 16, HH / 16, BB);
    repack_k<<<980, 256, 0, stream>>>(wsrc, Wd);
    conv_first<<<g, blk, 0, stream>>>(est, Wd + 248832, b_first, X);
    conv_mfma<true,  false><<<g, blk, 0, stream>>>(X, Wd + 0,      b1a, nullptr, T);
    conv_mfma<false, true ><<<g, blk, 0, stream>>>(T, Wd + 36864,  b1b, X, X);
    conv_mfma<true,  false><<<g, blk, 0, stream>>>(X, Wd + 73728,  b2a, nullptr, T);
    conv_mfma<false, true ><<<g, blk, 0, stream>>>(T, Wd + 110592, b2b, X, X);
    conv_mfma<true,  false><<<g, blk, 0, stream>>>(X, Wd + 147456, b3a, nullptr, T);
    conv_mfma<false, true ><<<g, blk, 0, stream>>>(T, Wd + 184320, b3b, X, X);
    conv_kpn<<<g, blk, 0, stream>>>(X, Wd + 221184, b_out, data, (float*)d_out);
}

// Round 9
// 325.190 us; speedup vs baseline: 1.2076x; 1.2076x over previous
//
#include <hip/hip_runtime.h>

#define HH 384
#define WW 384
#define BB 2

typedef unsigned short ushort_t;
typedef short  s16x8 __attribute__((ext_vector_type(8)));
typedef float  f32x4 __attribute__((ext_vector_type(4)));
typedef int    i32x4 __attribute__((ext_vector_type(4)));
typedef int    i32x2 __attribute__((ext_vector_type(2)));

union V16 { i32x4 i4; s16x8 v; ushort_t h[8]; };
union V8  { i32x2 i2; ushort_t h[4]; };

__device__ __forceinline__ ushort_t f2b(float f) {           // RNE fp32->bf16
    unsigned u = __builtin_bit_cast(unsigned, f);
    u += 0x7fffu + ((u >> 16) & 1u);
    return (ushort_t)(u >> 16);
}
__device__ __forceinline__ float b2f(ushort_t h) {
    return __builtin_bit_cast(float, ((unsigned)h) << 16);
}

// ---------------------------------------------------------------------------
// Weight repack. s-major so each 32-ci chunk is contiguous (LDS-stageable).
// Main convs j=0..5: [s(2)][t(9)][mt(4)][lane(64)][i(8)], 36864 each.
// w_out: [s(2)][t(9)][mt(3)][lane][i]: 27648.  w_first: [mt(4)][lane][i]: 2048.
// ---------------------------------------------------------------------------
struct WSrc { const float* p[8]; };

__global__ __launch_bounds__(256)
void repack_k(WSrc ws, ushort_t* __restrict__ Wd)
{
    const int idx = blockIdx.x * 256 + threadIdx.x;
    float val = 0.f;
    if (idx < 221184) {
        const int j = idx / 36864, rem = idx - j * 36864;
        const int i = rem & 7, lane = (rem >> 3) & 63;
        const int f = rem >> 9;                  // (s*9+t)*4+mt
        const int mt = f & 3, st = f >> 2;
        const int t = st % 9, s = st / 9;
        const int co = mt * 16 + (lane & 15);
        const int ci = s * 32 + (lane >> 4) * 8 + i;
        val = ws.p[j][((size_t)(co * 64 + ci)) * 9 + t];
    } else if (idx < 248832) {
        const int rem = idx - 221184;
        const int i = rem & 7, lane = (rem >> 3) & 63;
        const int f = rem >> 9;                  // (s*9+t)*3+mt
        const int mt = f % 3, st = f / 3;
        const int t = st % 9, s = st / 9;
        const int co = mt * 16 + (lane & 15);
        const int ci = s * 32 + (lane >> 4) * 8 + i;
        val = (co < 35) ? ws.p[6][((size_t)(co * 64 + ci)) * 9 + t] : 0.f;
    } else {
        const int rem = idx - 248832;            // < 2048
        const int i = rem & 7, lane = (rem >> 3) & 63;
        const int mt = rem >> 9;
        const int co = mt * 16 + (lane & 15);
        const int k = (lane >> 4) * 8 + i;
        if (k < 18) {
            const int ch = (k >= 9) ? 1 : 0;
            const int t = k - ch * 9;
            val = ws.p[7][((size_t)(co * 2 + ch)) * 9 + t];
        }
    }
    if (idx < 250880) Wd[idx] = f2b(val);
}

// ---------------------------------------------------------------------------
// Main conv: implicit GEMM, ALL-LDS inner loop (R7 structure: one weight-half
// swap, 78.3 KB LDS, 2 blocks/CU). R9: kx-major / ky-inner loop so the 6
// overlapping act rows are read ONCE per (chunk,kx): LDS reads 144->108/wave.
// R8 lesson: fine-grained weight streaming (12 MFMAs/barrier) spills + exposes
// latency at every barrier — half-chunk granularity minimum.
// R3 lesson: never cap VGPRs below the live set — spill goes to HBM scratch.
// ---------------------------------------------------------------------------
template<bool RELU, bool RES>
__global__ __launch_bounds__(256, 2)
void conv_mfma(const ushort_t* __restrict__ in, const ushort_t* __restrict__ wp,
               const float* __restrict__ bias, const ushort_t* __restrict__ res,
               ushort_t* __restrict__ out)
{
    __shared__ __align__(16) char smem[41472 + 36864];
    i32x4* s4 = (i32x4*)smem;                    // act: [(r*8+oct)*18 + x]
    i32x4* sw = (i32x4*)(smem + 41472);          // wgt chunk: [(t*4+mt)*64+lane]

    const int tid = threadIdx.x;
    const int x0 = blockIdx.x * 16, y0 = blockIdx.y * 16, b = blockIdx.z;
    const int lane = tid & 63, w4 = (tid >> 6) * 4;
    const int n = lane & 15, q = lane >> 4;

    // ---- batched staging: act (11 loads) + wgt chunk0 (9 loads) in flight ----
    {
        i32x4 ta[11];
#pragma unroll
        for (int k = 0; k < 11; ++k) {
            const int idx = tid + k * 256;
            ta[k] = 0;
            if (idx < 2592) {
                const int oct = idx & 7, p = idx >> 3;
                const int r = p / 18, xx = p - r * 18;
                const int gy = y0 - 1 + r, gx = x0 - 1 + xx;
                if ((unsigned)gy < HH && (unsigned)gx < WW)
                    ta[k] = *(const i32x4*)(in +
                        ((size_t)((b * HH + gy) * WW + gx)) * 64 + oct * 8);
            }
        }
        i32x4 tw[9];
#pragma unroll
        for (int k = 0; k < 9; ++k)
            tw[k] = *(const i32x4*)(wp + (size_t)(tid + k * 256) * 8);
#pragma unroll
        for (int k = 0; k < 11; ++k) {
            const int idx = tid + k * 256;
            if (idx < 2592) {
                const int oct = idx & 7, p = idx >> 3;
                const int r = p / 18, xx = p - r * 18;
                s4[(r * 8 + oct) * 18 + xx] = ta[k];
            }
        }
#pragma unroll
        for (int k = 0; k < 9; ++k)
            sw[tid + k * 256] = tw[k];
    }
    __syncthreads();

    f32x4 acc[4][4];
#pragma unroll
    for (int i = 0; i < 4; ++i)
#pragma unroll
        for (int j = 0; j < 4; ++j) acc[i][j] = 0.f;

    // prefetch wgt chunk1 into regs (retires behind chunk-0 compute).
    // chunk1 = slots 2304..4607 (element 18432 onward).
    i32x4 pw[9];
#pragma unroll
    for (int k = 0; k < 9; ++k)
        pw[k] = *(const i32x4*)(wp + (size_t)(2304 + tid + k * 256) * 8);

    // ---- chunk 0 (ci 0..31): kx-major, 6 bf rows reused across ky ----
#pragma unroll
    for (int kx = 0; kx < 3; ++kx) {
        V16 bf[6];
#pragma unroll
        for (int rr = 0; rr < 6; ++rr)
            bf[rr].i4 = s4[((w4 + rr) * 8 + q) * 18 + (n + kx)];
#pragma unroll
        for (int ky = 0; ky < 3; ++ky) {
#pragma unroll
            for (int mt = 0; mt < 4; ++mt) {
                V16 af; af.i4 = sw[((ky * 3 + kx) * 4 + mt) * 64 + lane];
#pragma unroll
                for (int nt = 0; nt < 4; ++nt)
                    acc[nt][mt] = __builtin_amdgcn_mfma_f32_16x16x32_bf16(
                        af.v, bf[nt + ky].v, acc[nt][mt], 0, 0, 0);
            }
        }
    }

    __syncthreads();                             // chunk0 wgt reads done
#pragma unroll
    for (int k = 0; k < 9; ++k)
        sw[tid + k * 256] = pw[k];
    __syncthreads();

    // ---- chunk 1 (ci 32..63) ----
#pragma unroll
    for (int kx = 0; kx < 3; ++kx) {
        V16 bf[6];
#pragma unroll
        for (int rr = 0; rr < 6; ++rr)
            bf[rr].i4 = s4[((w4 + rr) * 8 + 4 + q) * 18 + (n + kx)];
#pragma unroll
        for (int ky = 0; ky < 3; ++ky) {
#pragma unroll
            for (int mt = 0; mt < 4; ++mt) {
                V16 af; af.i4 = sw[((ky * 3 + kx) * 4 + mt) * 64 + lane];
#pragma unroll
                for (int nt = 0; nt < 4; ++nt)
                    acc[nt][mt] = __builtin_amdgcn_mfma_f32_16x16x32_bf16(
                        af.v, bf[nt + ky].v, acc[nt][mt], 0, 0, 0);
            }
        }
    }

    // ---- transpose epilogue (aliases act region, 32 KB < 41.5 KB) ----
    __syncthreads();
#pragma unroll
    for (int nt = 0; nt < 4; ++nt) {
        const int row = w4 + nt;
#pragma unroll
        for (int mt = 0; mt < 4; ++mt) {
            const int co0 = mt * 16 + q * 4;
            const float4 bv = *(const float4*)(bias + co0);
            float vv[4] = {acc[nt][mt][0] + bv.x, acc[nt][mt][1] + bv.y,
                           acc[nt][mt][2] + bv.z, acc[nt][mt][3] + bv.w};
            V8 ov;
#pragma unroll
            for (int r = 0; r < 4; ++r)
                ov.h[r] = f2b(RELU ? fmaxf(vv[r], 0.f) : vv[r]);
            const int c = 2 * mt + (q >> 1);
            const int cpr = c ^ (n & 7);
            *(i32x2*)(smem + row * 2048 + n * 128 + cpr * 16 + (q & 1) * 8) = ov.i2;
        }
    }
    __syncthreads();
    // readback: 64 lanes x 16B = 1 KB contiguous per wave instruction;
    // residual added here (same coalesced pattern).
#pragma unroll
    for (int r0 = 0; r0 < 4; ++r0) {
        const int row = w4 + r0, y = y0 + row;
#pragma unroll
        for (int j = 0; j < 2; ++j) {
            const int px = (lane >> 3) + 8 * j;
            const int clin = lane & 7;
            const int cpr = clin ^ (px & 7);
            V16 v;
            v.i4 = *(const i32x4*)(smem + row * 2048 + px * 128 + cpr * 16);
            const size_t goff = ((size_t)((b * HH + y) * WW + x0 + px)) * 64
                                + clin * 8;
            if (RES) {
                V16 rv;
                rv.i4 = *(const i32x4*)(res + goff);
#pragma unroll
                for (int e = 0; e < 8; ++e)
                    v.h[e] = f2b(b2f(v.h[e]) + b2f(rv.h[e]));
            }
            *(i32x4*)(out + goff) = v.i4;
        }
    }
}

// ---------------------------------------------------------------------------
// First conv: CI=2 fp32 NCHW, K=18 padded to 32, transpose epilogue.
// ---------------------------------------------------------------------------
__global__ __launch_bounds__(256, 4)
void conv_first(const float* __restrict__ in, const ushort_t* __restrict__ wp,
                const float* __restrict__ bias, ushort_t* __restrict__ out)
{
    __shared__ float s_raw[2][18][20];
    __shared__ __align__(16) char epi[32768];
    const int tid = threadIdx.x;
    const int x0 = blockIdx.x * 16, y0 = blockIdx.y * 16, b = blockIdx.z;
    {
        float tmp[3];
#pragma unroll
        for (int k = 0; k < 3; ++k) {
            const int idx = tid + k * 256;
            tmp[k] = 0.f;
            if (idx < 648) {
                const int ch = idx / 324, rem = idx - ch * 324;
                const int r = rem / 18, x = rem - r * 18;
                const int gy = y0 - 1 + r, gx = x0 - 1 + x;
                if ((unsigned)gy < HH && (unsigned)gx < WW)
                    tmp[k] = in[((size_t)((b * 2 + ch) * HH + gy)) * WW + gx];
            }
        }
#pragma unroll
        for (int k = 0; k < 3; ++k) {
            const int idx = tid + k * 256;
            if (idx < 648) {
                const int ch = idx / 324, rem = idx - ch * 324;
                const int r = rem / 18, x = rem - r * 18;
                s_raw[ch][r][x] = tmp[k];
            }
        }
    }
    __syncthreads();

    const int lane = tid & 63, w4 = (tid >> 6) * 4;
    const int n = lane & 15, q = lane >> 4;

    V16 af[4];
#pragma unroll
    for (int mt = 0; mt < 4; ++mt)
        af[mt].i4 = *(const i32x4*)(wp + ((size_t)(mt * 64 + lane)) * 8);

    f32x4 acc[4][4];
#pragma unroll
    for (int i = 0; i < 4; ++i)
#pragma unroll
        for (int j = 0; j < 4; ++j) acc[i][j] = 0.f;

#pragma unroll
    for (int nt = 0; nt < 4; ++nt) {
        const int r = w4 + nt;
        V16 bf;
#pragma unroll
        for (int i = 0; i < 8; ++i) {
            const int k = q * 8 + i;
            float v = 0.f;
            if (k < 18) {
                const int ch = (k >= 9) ? 1 : 0;
                const int t = k - ch * 9;
                const int ky = t / 3, kx = t - ky * 3;
                v = s_raw[ch][r + ky][n + kx];
            }
            bf.h[i] = f2b(v);
        }
#pragma unroll
        for (int mt = 0; mt < 4; ++mt)
            acc[nt][mt] = __builtin_amdgcn_mfma_f32_16x16x32_bf16(
                af[mt].v, bf.v, acc[nt][mt], 0, 0, 0);
    }

#pragma unroll
    for (int nt = 0; nt < 4; ++nt) {
        const int row = w4 + nt;
#pragma unroll
        for (int mt = 0; mt < 4; ++mt) {
            const int co0 = mt * 16 + q * 4;
            const float4 bv = *(const float4*)(bias + co0);
            V8 ov;
            ov.h[0] = f2b(acc[nt][mt][0] + bv.x);
            ov.h[1] = f2b(acc[nt][mt][1] + bv.y);
            ov.h[2] = f2b(acc[nt][mt][2] + bv.z);
            ov.h[3] = f2b(acc[nt][mt][3] + bv.w);
            const int c = 2 * mt + (q >> 1);
            const int cpr = c ^ (n & 7);
            *(i32x2*)(epi + row * 2048 + n * 128 + cpr * 16 + (q & 1) * 8) = ov.i2;
        }
    }
    __syncthreads();
#pragma unroll
    for (int r0 = 0; r0 < 4; ++r0) {
        const int row = w4 + r0, y = y0 + row;
#pragma unroll
        for (int j = 0; j < 2; ++j) {
            const int px = (lane >> 3) + 8 * j;
            const int clin = lane & 7;
            const int cpr = clin ^ (px & 7);
            i32x4 v = *(const i32x4*)(epi + row * 2048 + px * 128 + cpr * 16);
            *(i32x4*)(out + ((size_t)((b * HH + y) * WW + x0 + px)) * 64
                          + clin * 8) = v;
        }
    }
}

// ---------------------------------------------------------------------------
// KPN: array-free, d2-grouped, compile-time recursion (R5 — fixed the scratch
// spill). No max-subtraction: softmax ratio unchanged, |core| logits are small.
// ---------------------------------------------------------------------------
constexpr int isq_(int v) { int r = 0; while ((r + 1) * (r + 1) <= v) ++r; return r; }
constexpr double csqrt_(int x) {
    double g = x ? (double)x : 0.0;
    if (x) for (int i = 0; i < 80; ++i) g = 0.5 * (g + (double)x / g);
    return g;
}
constexpr int tapm_(int W, int d2) {
    const int R = W - 1; int c = 0;
    for (int di = -R; di <= R; ++di)
        for (int dj = -R; dj <= R; ++dj)
            if (di * di + dj * dj == d2) ++c;
    return c;
}
constexpr int nout_(int W) {
    const int R = W - 1; int c = 0;
    for (int di = -R; di <= R; ++di)
        for (int dj = -R; dj <= R; ++dj)
            if (di * di + dj * dj > R * R) ++c;
    return c;
}

template<int W, int D2, int DI>
struct DiSum {
    static constexpr int R = W - 1;
    static __device__ __forceinline__ float run(const float* s_f, int base) {
        float s = 0.f;
        constexpr int rem = D2 - DI * DI;
        if constexpr (rem >= 0) {
            constexpr int sj = isq_(rem >= 0 ? rem : 0);
            if constexpr (sj * sj == rem) {
                s += s_f[base + DI * 48 + sj];
                if constexpr (sj > 0) s += s_f[base + DI * 48 - sj];
            }
        }
        if constexpr (DI < R) s += DiSum<W, D2, DI + 1>::run(s_f, base);
        return s;
    }
};

template<int W, int OFF, int D2>
struct D2Loop {
    static __device__ __forceinline__ void run(const float* cv, const float* s_f,
                                               int base, float& num, float& den) {
        constexpr int m = tapm_(W, D2);
        if constexpr (m > 0) {
            constexpr int lo = isq_(D2);
            float v;
            if constexpr (lo * lo == D2) {
                v = cv[OFF + lo];
            } else {
                constexpr float fr = (float)(csqrt_(D2) - (double)lo);
                v = __builtin_fmaf(fr, cv[OFF + lo + 1] - cv[OFF + lo], cv[OFF + lo]);
            }
            const float e = __expf(v);
            const float S = DiSum<W, D2, -(W - 1)>::run(s_f, base);
            num = __builtin_fmaf(e, S, num);
            den = __builtin_fmaf((float)m, e, den);
        }
        if constexpr (D2 > 0)
            D2Loop<W, OFF, D2 - 1>::run(cv, s_f, base, num, den);
    }
};

template<int W, int OFF>
__device__ __forceinline__ float kpn_section(const float* cv, const float* s_f,
                                             int base)
{
    constexpr int R = W - 1, R2 = R * R;
    float sout = 0.f;                            // outside taps: e = exp(0) = 1
#pragma unroll
    for (int di = -R; di <= R; ++di)
#pragma unroll
        for (int dj = -R; dj <= R; ++dj)
            if (di * di + dj * dj > R2)
                sout += s_f[base + di * 48 + dj];
    float num = sout, den = (float)nout_(W);
    D2Loop<W, OFF, R2>::run(cv, s_f, base, num, den);
    return num / den;
}

// ---------------------------------------------------------------------------
// Fused out-conv (64->35, COT=3) + KPN, all-LDS inner loop (R7 structure,
// one weight-half swap; R9 kx-major bf reuse).
// LDS: stage 41472 (aliased by core 256x37 fp32) + frames 5760 + wgt 27648.
// w_out chunk1 = slots 1728..3455 (element 13824 onward).
// ---------------------------------------------------------------------------
__global__ __launch_bounds__(256, 2)
void conv_kpn(const ushort_t* __restrict__ in, const ushort_t* __restrict__ wp,
              const float* __restrict__ bias, const float* __restrict__ frames,
              float* __restrict__ out)
{
    __shared__ __align__(16) char smem[41472 + 5760 + 27648];
    i32x4* s4 = (i32x4*)smem;                    // stage [(r*8+oct)*18+x]
    float* s_core = (float*)smem;                // [px 256][ch 37]
    float* s_f = (float*)(smem + 41472);         // frames 30x48
    i32x4* sw = (i32x4*)(smem + 41472 + 5760);   // wgt chunk: 1728 slots

    const int tid = threadIdx.x;
    const int x0 = blockIdx.x * 16, y0 = blockIdx.y * 16, b = blockIdx.z;

    {
        i32x4 ta[11];
#pragma unroll
        for (int k = 0; k < 11; ++k) {
            const int idx = tid + k * 256;
            ta[k] = 0;
            if (idx < 2592) {
                const int oct = idx & 7, p = idx >> 3;
                const int r = p / 18, xx = p - r * 18;
                const int gy = y0 - 1 + r, gx = x0 - 1 + xx;
                if ((unsigned)gy < HH && (unsigned)gx < WW)
                    ta[k] = *(const i32x4*)(in +
                        ((size_t)((b * HH + gy) * WW + gx)) * 64 + oct * 8);
            }
        }
        float ff[4];
#pragma unroll
        for (int k = 0; k < 4; ++k) {
            const int idx = tid + k * 256;
            ff[k] = 0.f;
            if (idx < 900) {
                const int r = idx / 30, c = idx - r * 30;
                const int y = y0 - 7 + r, x = x0 - 7 + c;
                if ((unsigned)y < HH && (unsigned)x < WW)
                    ff[k] = frames[((size_t)b * HH + y) * WW + x];
            }
        }
        i32x4 tw[7];
#pragma unroll
        for (int k = 0; k < 7; ++k) {
            const int idx = tid + k * 256;
            tw[k] = 0;
            if (idx < 1728)
                tw[k] = *(const i32x4*)(wp + (size_t)idx * 8);
        }
#pragma unroll
        for (int k = 0; k < 11; ++k) {
            const int idx = tid + k * 256;
            if (idx < 2592) {
                const int oct = idx & 7, p = idx >> 3;
                const int r = p / 18, xx = p - r * 18;
                s4[(r * 8 + oct) * 18 + xx] = ta[k];
            }
        }
#pragma unroll
        for (int k = 0; k < 4; ++k) {
            const int idx = tid + k * 256;
            if (idx < 900) {
                const int r = idx / 30, c = idx - r * 30;
                s_f[r * 48 + c] = ff[k];
            }
        }
#pragma unroll
        for (int k = 0; k < 7; ++k) {
            const int idx = tid + k * 256;
            if (idx < 1728) sw[idx] = tw[k];
        }
    }
    __syncthreads();

    const int lane = tid & 63, w4 = (tid >> 6) * 4;
    const int n = lane & 15, q = lane >> 4;

    f32x4 acc[4][3];
#pragma unroll
    for (int i = 0; i < 4; ++i)
#pragma unroll
        for (int j = 0; j < 3; ++j) acc[i][j] = 0.f;

    // prefetch wgt chunk1 (slots 1728..3455)
    i32x4 pw[7];
#pragma unroll
    for (int k = 0; k < 7; ++k) {
        const int idx = tid + k * 256;
        pw[k] = 0;
        if (idx < 1728)
            pw[k] = *(const i32x4*)(wp + (size_t)(1728 + idx) * 8);
    }

    // ---- chunk 0: kx-major, 6 bf rows reused across ky ----
#pragma unroll
    for (int kx = 0; kx < 3; ++kx) {
        V16 bf[6];
#pragma unroll
        for (int rr = 0; rr < 6; ++rr)
            bf[rr].i4 = s4[((w4 + rr) * 8 + q) * 18 + (n + kx)];
#pragma unroll
        for (int ky = 0; ky < 3; ++ky) {
#pragma unroll
            for (int mt = 0; mt < 3; ++mt) {
                V16 af; af.i4 = sw[((ky * 3 + kx) * 3 + mt) * 64 + lane];
#pragma unroll
                for (int nt = 0; nt < 4; ++nt)
                    acc[nt][mt] = __builtin_amdgcn_mfma_f32_16x16x32_bf16(
                        af.v, bf[nt + ky].v, acc[nt][mt], 0, 0, 0);
            }
        }
    }

    __syncthreads();
#pragma unroll
    for (int k = 0; k < 7; ++k) {
        const int idx = tid + k * 256;
        if (idx < 1728) sw[idx] = pw[k];
    }
    __syncthreads();

    // ---- chunk 1 ----
#pragma unroll
    for (int kx = 0; kx < 3; ++kx) {
        V16 bf[6];
#pragma unroll
        for (int rr = 0; rr < 6; ++rr)
            bf[rr].i4 = s4[((w4 + rr) * 8 + 4 + q) * 18 + (n + kx)];
#pragma unroll
        for (int ky = 0; ky < 3; ++ky) {
#pragma unroll
            for (int mt = 0; mt < 3; ++mt) {
                V16 af; af.i4 = sw[((ky * 3 + kx) * 3 + mt) * 64 + lane];
#pragma unroll
                for (int nt = 0; nt < 4; ++nt)
                    acc[nt][mt] = __builtin_amdgcn_mfma_f32_16x16x32_bf16(
                        af.v, bf[nt + ky].v, acc[nt][mt], 0, 0, 0);
            }
        }
    }

    __syncthreads();                             // stage reads done; write core
#pragma unroll
    for (int nt = 0; nt < 4; ++nt) {
        const int px = (w4 + nt) * 16 + n;
#pragma unroll
        for (int mt = 0; mt < 3; ++mt) {
#pragma unroll
            for (int r = 0; r < 4; ++r) {
                const int ch = mt * 16 + q * 4 + r;
                if (ch < 35)
                    s_core[px * 37 + ch] = fabsf(acc[nt][mt][r] + bias[ch]);
            }
        }
    }
    __syncthreads();

    const int ty = tid >> 4, tx = tid & 15;
    const int base = (ty + 7) * 48 + (tx + 7);
    const float* cv = s_core + tid * 37;
    float pred = 0.f;
    pred += kpn_section<2, 0>(cv, s_f, base);
    pred += kpn_section<3, 2>(cv, s_f, base);
    pred += kpn_section<4, 5>(cv, s_f, base);
    pred += kpn_section<5, 9>(cv, s_f, base);
    pred += kpn_section<6, 14>(cv, s_f, base);
    pred += kpn_section<7, 20>(cv, s_f, base);
    pred += kpn_section<8, 27>(cv, s_f, base);
    out[((size_t)b * HH + y0 + ty) * WW + x0 + tx] = pred;
}

// ---------------------------------------------------------------------------
extern "C" void kernel_launch(void* const* d_in, const int* in_sizes, int n_in,
                              void* d_out, int out_size, void* d_ws, size_t ws_size,
                              hipStream_t stream)
{
    const float* est     = (const float*)d_in[0];
    const float* data    = (const float*)d_in[1];
    const float* w_first = (const float*)d_in[2];
    const float* b_first = (const float*)d_in[3];
    const float* w1a = (const float*)d_in[4];
    const float* b1a = (const float*)d_in[5];
    const float* w1b = (const float*)d_in[6];
    const float* b1b = (const float*)d_in[7];
    const float* w2a = (const float*)d_in[8];
    const float* b2a = (const float*)d_in[9];
    const float* w2b = (const float*)d_in[10];
    const float* b2b = (const float*)d_in[11];
    const float* w3a = (const float*)d_in[12];
    const float* b3a = (const float*)d_in[13];
    const float* w3b = (const float*)d_in[14];
    const float* b3b = (const float*)d_in[15];
    const float* w_out = (const float*)d_in[16];
    const float* b_out = (const float*)d_in[17];

    ushort_t* X  = (ushort_t*)d_ws;                         // NHWC bf16 (B,H,W,64)
    ushort_t* T  = X + (size_t)BB * HH * WW * 64;
    ushort_t* Wd = T + (size_t)BB * HH * WW * 64;           // repacked weights

    WSrc wsrc;
    wsrc.p[0] = w1a; wsrc.p[1] = w1b; wsrc.p[2] = w2a; wsrc.p[3] = w2b;
    wsrc.p[4] = w3a; wsrc.p[5] = w3b; wsrc.p[6] = w_out; wsrc.p[7] = w_first;

    dim3 blk(256), g(WW / 16, HH / 16, BB);
    repack_k<<<980, 256, 0, stream>>>(wsrc, Wd);
    conv_first<<<g, blk, 0, stream>>>(est, Wd + 248832, b_first, X);
    conv_mfma<true,  false><<<g, blk, 0, stream>>>(X, Wd + 0,      b1a, nullptr, T);
    conv_mfma<false, true ><<<g, blk, 0, stream>>>(T, Wd + 36864,  b1b, X, X);
    conv_mfma<true,  false><<<g, blk, 0, stream>>>(X, Wd + 73728,  b2a, nullptr, T);
    conv_mfma<false, true ><<<g, blk, 0, stream>>>(T, Wd + 110592, b2b, X, X);
    conv_mfma<true,  false><<<g, blk, 0, stream>>>(X, Wd + 147456, b3a, nullptr, T);
    conv_mfma<false, true ><<<g, blk, 0, stream>>>(T, Wd + 184320, b3b, X, X);
    conv_kpn<<<g, blk, 0, stream>>>(X, Wd + 221184, b_out, data, (float*)d_out);
}

// Round 10
// 312.079 us; speedup vs baseline: 1.2584x; 1.0420x over previous
//
#include <hip/hip_runtime.h>

#define HH 384
#define WW 384
#define BB 2

typedef unsigned short ushort_t;
typedef short  s16x8 __attribute__((ext_vector_type(8)));
typedef float  f32x4 __attribute__((ext_vector_type(4)));
typedef int    i32x4 __attribute__((ext_vector_type(4)));
typedef int    i32x2 __attribute__((ext_vector_type(2)));

union V16 { i32x4 i4; s16x8 v; ushort_t h[8]; };
union V8  { i32x2 i2; ushort_t h[4]; };

__device__ __forceinline__ ushort_t f2b(float f) {           // RNE fp32->bf16
    unsigned u = __builtin_bit_cast(unsigned, f);
    u += 0x7fffu + ((u >> 16) & 1u);
    return (ushort_t)(u >> 16);
}
__device__ __forceinline__ float b2f(ushort_t h) {
    return __builtin_bit_cast(float, ((unsigned)h) << 16);
}

// ---------------------------------------------------------------------------
// Weight repack. s-major so each 32-ci chunk is contiguous (LDS-stageable).
// Main convs j=0..5: [s(2)][t(9)][mt(4)][lane(64)][i(8)], 36864 each.
// w_out: [s(2)][t(9)][mt(3)][lane][i]: 27648.  w_first: [mt(4)][lane][i]: 2048.
// ---------------------------------------------------------------------------
struct WSrc { const float* p[8]; };

__global__ __launch_bounds__(256)
void repack_k(WSrc ws, ushort_t* __restrict__ Wd)
{
    const int idx = blockIdx.x * 256 + threadIdx.x;
    float val = 0.f;
    if (idx < 221184) {
        const int j = idx / 36864, rem = idx - j * 36864;
        const int i = rem & 7, lane = (rem >> 3) & 63;
        const int f = rem >> 9;                  // (s*9+t)*4+mt
        const int mt = f & 3, st = f >> 2;
        const int t = st % 9, s = st / 9;
        const int co = mt * 16 + (lane & 15);
        const int ci = s * 32 + (lane >> 4) * 8 + i;
        val = ws.p[j][((size_t)(co * 64 + ci)) * 9 + t];
    } else if (idx < 248832) {
        const int rem = idx - 221184;
        const int i = rem & 7, lane = (rem >> 3) & 63;
        const int f = rem >> 9;                  // (s*9+t)*3+mt
        const int mt = f % 3, st = f / 3;
        const int t = st % 9, s = st / 9;
        const int co = mt * 16 + (lane & 15);
        const int ci = s * 32 + (lane >> 4) * 8 + i;
        val = (co < 35) ? ws.p[6][((size_t)(co * 64 + ci)) * 9 + t] : 0.f;
    } else {
        const int rem = idx - 248832;            // < 2048
        const int i = rem & 7, lane = (rem >> 3) & 63;
        const int mt = rem >> 9;
        const int co = mt * 16 + (lane & 15);
        const int k = (lane >> 4) * 8 + i;
        if (k < 18) {
            const int ch = (k >= 9) ? 1 : 0;
            const int t = k - ch * 9;
            val = ws.p[7][((size_t)(co * 2 + ch)) * 9 + t];
        }
    }
    if (idx < 250880) Wd[idx] = f2b(val);
}

// ---------------------------------------------------------------------------
// Main conv: implicit GEMM, ALL-LDS inner loop (R7 structure — proven best:
// one weight-half swap, 78.3 KB LDS, 2 blocks/CU, t-major K-loop).
// R8 lesson: fine weight streaming (12 MFMAs/barrier) spills + exposes latency.
// R9 lesson: kx-major bf[6] reuse widens live ranges and regresses.
// R3 lesson: never cap VGPRs below the live set — spill goes to HBM scratch.
// ---------------------------------------------------------------------------
template<bool RELU, bool RES>
__global__ __launch_bounds__(256, 2)
void conv_mfma(const ushort_t* __restrict__ in, const ushort_t* __restrict__ wp,
               const float* __restrict__ bias, const ushort_t* __restrict__ res,
               ushort_t* __restrict__ out)
{
    __shared__ __align__(16) char smem[41472 + 36864];
    i32x4* s4 = (i32x4*)smem;                    // act: [(r*8+oct)*18 + x]
    i32x4* sw = (i32x4*)(smem + 41472);          // wgt chunk: [(t*4+mt)*64+lane]

    const int tid = threadIdx.x;
    const int x0 = blockIdx.x * 16, y0 = blockIdx.y * 16, b = blockIdx.z;
    const int lane = tid & 63, w4 = (tid >> 6) * 4;
    const int n = lane & 15, q = lane >> 4;

    // ---- batched staging: act (11 loads) + wgt chunk0 (9 loads) in flight ----
    {
        i32x4 ta[11];
#pragma unroll
        for (int k = 0; k < 11; ++k) {
            const int idx = tid + k * 256;
            ta[k] = 0;
            if (idx < 2592) {
                const int oct = idx & 7, p = idx >> 3;
                const int r = p / 18, xx = p - r * 18;
                const int gy = y0 - 1 + r, gx = x0 - 1 + xx;
                if ((unsigned)gy < HH && (unsigned)gx < WW)
                    ta[k] = *(const i32x4*)(in +
                        ((size_t)((b * HH + gy) * WW + gx)) * 64 + oct * 8);
            }
        }
        i32x4 tw[9];
#pragma unroll
        for (int k = 0; k < 9; ++k)
            tw[k] = *(const i32x4*)(wp + (size_t)(tid + k * 256) * 8);
#pragma unroll
        for (int k = 0; k < 11; ++k) {
            const int idx = tid + k * 256;
            if (idx < 2592) {
                const int oct = idx & 7, p = idx >> 3;
                const int r = p / 18, xx = p - r * 18;
                s4[(r * 8 + oct) * 18 + xx] = ta[k];
            }
        }
#pragma unroll
        for (int k = 0; k < 9; ++k)
            sw[tid + k * 256] = tw[k];
    }
    __syncthreads();

    f32x4 acc[4][4];
#pragma unroll
    for (int i = 0; i < 4; ++i)
#pragma unroll
        for (int j = 0; j < 4; ++j) acc[i][j] = 0.f;

    // prefetch wgt chunk1 into regs (retires behind chunk-0 compute).
    // chunk1 = slots 2304..4607 (element 18432 onward).
    i32x4 pw[9];
#pragma unroll
    for (int k = 0; k < 9; ++k)
        pw[k] = *(const i32x4*)(wp + (size_t)(2304 + tid + k * 256) * 8);

    // ---- chunk 0 (ci 0..31): all-LDS, t-major ----
#pragma unroll
    for (int t = 0; t < 9; ++t) {
        const int ky = t / 3, kx = t - ky * 3;
        V16 bf[4];
#pragma unroll
        for (int nt = 0; nt < 4; ++nt)
            bf[nt].i4 = s4[((w4 + nt + ky) * 8 + q) * 18 + (n + kx)];
#pragma unroll
        for (int mt = 0; mt < 4; ++mt) {
            V16 af; af.i4 = sw[(t * 4 + mt) * 64 + lane];
#pragma unroll
            for (int nt = 0; nt < 4; ++nt)
                acc[nt][mt] = __builtin_amdgcn_mfma_f32_16x16x32_bf16(
                    af.v, bf[nt].v, acc[nt][mt], 0, 0, 0);
        }
    }

    __syncthreads();                             // chunk0 wgt reads done
#pragma unroll
    for (int k = 0; k < 9; ++k)
        sw[tid + k * 256] = pw[k];
    __syncthreads();

    // ---- chunk 1 (ci 32..63) ----
#pragma unroll
    for (int t = 0; t < 9; ++t) {
        const int ky = t / 3, kx = t - ky * 3;
        V16 bf[4];
#pragma unroll
        for (int nt = 0; nt < 4; ++nt)
            bf[nt].i4 = s4[((w4 + nt + ky) * 8 + 4 + q) * 18 + (n + kx)];
#pragma unroll
        for (int mt = 0; mt < 4; ++mt) {
            V16 af; af.i4 = sw[(t * 4 + mt) * 64 + lane];
#pragma unroll
            for (int nt = 0; nt < 4; ++nt)
                acc[nt][mt] = __builtin_amdgcn_mfma_f32_16x16x32_bf16(
                    af.v, bf[nt].v, acc[nt][mt], 0, 0, 0);
        }
    }

    // ---- transpose epilogue (aliases act region, 32 KB < 41.5 KB) ----
    __syncthreads();
#pragma unroll
    for (int nt = 0; nt < 4; ++nt) {
        const int row = w4 + nt;
#pragma unroll
        for (int mt = 0; mt < 4; ++mt) {
            const int co0 = mt * 16 + q * 4;
            const float4 bv = *(const float4*)(bias + co0);
            float vv[4] = {acc[nt][mt][0] + bv.x, acc[nt][mt][1] + bv.y,
                           acc[nt][mt][2] + bv.z, acc[nt][mt][3] + bv.w};
            V8 ov;
#pragma unroll
            for (int r = 0; r < 4; ++r)
                ov.h[r] = f2b(RELU ? fmaxf(vv[r], 0.f) : vv[r]);
            const int c = 2 * mt + (q >> 1);
            const int cpr = c ^ (n & 7);
            *(i32x2*)(smem + row * 2048 + n * 128 + cpr * 16 + (q & 1) * 8) = ov.i2;
        }
    }
    __syncthreads();
    // readback: 64 lanes x 16B = 1 KB contiguous per wave instruction;
    // residual added here (same coalesced pattern).
#pragma unroll
    for (int r0 = 0; r0 < 4; ++r0) {
        const int row = w4 + r0, y = y0 + row;
#pragma unroll
        for (int j = 0; j < 2; ++j) {
            const int px = (lane >> 3) + 8 * j;
            const int clin = lane & 7;
            const int cpr = clin ^ (px & 7);
            V16 v;
            v.i4 = *(const i32x4*)(smem + row * 2048 + px * 128 + cpr * 16);
            const size_t goff = ((size_t)((b * HH + y) * WW + x0 + px)) * 64
                                + clin * 8;
            if (RES) {
                V16 rv;
                rv.i4 = *(const i32x4*)(res + goff);
#pragma unroll
                for (int e = 0; e < 8; ++e)
                    v.h[e] = f2b(b2f(v.h[e]) + b2f(rv.h[e]));
            }
            *(i32x4*)(out + goff) = v.i4;
        }
    }
}

// ---------------------------------------------------------------------------
// First conv: CI=2 fp32 NCHW, K=18 padded to 32, transpose epilogue.
// ---------------------------------------------------------------------------
__global__ __launch_bounds__(256, 4)
void conv_first(const float* __restrict__ in, const ushort_t* __restrict__ wp,
                const float* __restrict__ bias, ushort_t* __restrict__ out)
{
    __shared__ float s_raw[2][18][20];
    __shared__ __align__(16) char epi[32768];
    const int tid = threadIdx.x;
    const int x0 = blockIdx.x * 16, y0 = blockIdx.y * 16, b = blockIdx.z;
    {
        float tmp[3];
#pragma unroll
        for (int k = 0; k < 3; ++k) {
            const int idx = tid + k * 256;
            tmp[k] = 0.f;
            if (idx < 648) {
                const int ch = idx / 324, rem = idx - ch * 324;
                const int r = rem / 18, x = rem - r * 18;
                const int gy = y0 - 1 + r, gx = x0 - 1 + x;
                if ((unsigned)gy < HH && (unsigned)gx < WW)
                    tmp[k] = in[((size_t)((b * 2 + ch) * HH + gy)) * WW + gx];
            }
        }
#pragma unroll
        for (int k = 0; k < 3; ++k) {
            const int idx = tid + k * 256;
            if (idx < 648) {
                const int ch = idx / 324, rem = idx - ch * 324;
                const int r = rem / 18, x = rem - r * 18;
                s_raw[ch][r][x] = tmp[k];
            }
        }
    }
    __syncthreads();

    const int lane = tid & 63, w4 = (tid >> 6) * 4;
    const int n = lane & 15, q = lane >> 4;

    V16 af[4];
#pragma unroll
    for (int mt = 0; mt < 4; ++mt)
        af[mt].i4 = *(const i32x4*)(wp + ((size_t)(mt * 64 + lane)) * 8);

    f32x4 acc[4][4];
#pragma unroll
    for (int i = 0; i < 4; ++i)
#pragma unroll
        for (int j = 0; j < 4; ++j) acc[i][j] = 0.f;

#pragma unroll
    for (int nt = 0; nt < 4; ++nt) {
        const int r = w4 + nt;
        V16 bf;
#pragma unroll
        for (int i = 0; i < 8; ++i) {
            const int k = q * 8 + i;
            float v = 0.f;
            if (k < 18) {
                const int ch = (k >= 9) ? 1 : 0;
                const int t = k - ch * 9;
                const int ky = t / 3, kx = t - ky * 3;
                v = s_raw[ch][r + ky][n + kx];
            }
            bf.h[i] = f2b(v);
        }
#pragma unroll
        for (int mt = 0; mt < 4; ++mt)
            acc[nt][mt] = __builtin_amdgcn_mfma_f32_16x16x32_bf16(
                af[mt].v, bf.v, acc[nt][mt], 0, 0, 0);
    }

#pragma unroll
    for (int nt = 0; nt < 4; ++nt) {
        const int row = w4 + nt;
#pragma unroll
        for (int mt = 0; mt < 4; ++mt) {
            const int co0 = mt * 16 + q * 4;
            const float4 bv = *(const float4*)(bias + co0);
            V8 ov;
            ov.h[0] = f2b(acc[nt][mt][0] + bv.x);
            ov.h[1] = f2b(acc[nt][mt][1] + bv.y);
            ov.h[2] = f2b(acc[nt][mt][2] + bv.z);
            ov.h[3] = f2b(acc[nt][mt][3] + bv.w);
            const int c = 2 * mt + (q >> 1);
            const int cpr = c ^ (n & 7);
            *(i32x2*)(epi + row * 2048 + n * 128 + cpr * 16 + (q & 1) * 8) = ov.i2;
        }
    }
    __syncthreads();
#pragma unroll
    for (int r0 = 0; r0 < 4; ++r0) {
        const int row = w4 + r0, y = y0 + row;
#pragma unroll
        for (int j = 0; j < 2; ++j) {
            const int px = (lane >> 3) + 8 * j;
            const int clin = lane & 7;
            const int cpr = clin ^ (px & 7);
            i32x4 v = *(const i32x4*)(epi + row * 2048 + px * 128 + cpr * 16);
            *(i32x4*)(out + ((size_t)((b * HH + y) * WW + x0 + px)) * 64
                          + clin * 8) = v;
        }
    }
}

// ---------------------------------------------------------------------------
// KPN v3: single tap pass over Chebyshev rings m=0..7, grouped by d2=m^2+k^2.
// Each frame tap read ONCE (225 b32 LDS reads vs 679 in the per-section
// version); its ring-group sum feeds all 7 sections' num/den accumulators
// (sections nest: ring m belongs to every section with R>=m). den accumulates
// in the same pass (mult*e). No max-subtraction (validated since R5). Only
// 7-float constant-indexed accumulators — SROA-safe (R4 lesson: big arrays
// spill to scratch; tripwire = kpn WRITE_SIZE must stay ~1.2 MB).
// ---------------------------------------------------------------------------
constexpr int isq_(int v) { int r = 0; while ((r + 1) * (r + 1) <= v) ++r; return r; }
constexpr double csqrt_(int x) {
    double g = x ? (double)x : 0.0;
    if (x) for (int i = 0; i < 80; ++i) g = 0.5 * (g + (double)x / g);
    return g;
}
constexpr int ringmult_(int m, int k) {
    if (m == 0) return 1;
    if (k == 0 || k == m) return 4;
    return 8;
}
constexpr int OFFS_(int s) {                     // channel offset per section
    return s == 0 ? 0 : s == 1 ? 2 : s == 2 ? 5 : s == 3 ? 9
         : s == 4 ? 14 : s == 5 ? 20 : 27;
}

template<int M, int K>
__device__ __forceinline__ float ringsum(const float* s_f, int base)
{
    if constexpr (M == 0) {
        return s_f[base];
    } else if constexpr (K == 0) {
        return s_f[base + M * 48] + s_f[base - M * 48]
             + s_f[base + M]      + s_f[base - M];
    } else if constexpr (K == M) {
        return s_f[base + M * 48 + M] + s_f[base + M * 48 - M]
             + s_f[base - M * 48 + M] + s_f[base - M * 48 - M];
    } else {
        return s_f[base + M * 48 + K] + s_f[base + M * 48 - K]
             + s_f[base - M * 48 + K] + s_f[base - M * 48 - K]
             + s_f[base + K * 48 + M] + s_f[base + K * 48 - M]
             + s_f[base - K * 48 + M] + s_f[base - K * 48 - M];
    }
}

template<int M, int K, int S>
struct SecAcc {
    static __device__ __forceinline__ void run(const float* cv, float Sv,
                                               float* num, float* den) {
        constexpr int R = S + 1;
        if constexpr (R >= M) {
            constexpr int d2 = M * M + K * K;
            constexpr int mult = ringmult_(M, K);
            constexpr int OFF = OFFS_(S);
            if constexpr (d2 <= R * R) {
                constexpr int lo = isq_(d2);
                float v;
                if constexpr (lo * lo == d2) {
                    v = cv[OFF + lo];
                } else {
                    constexpr float fr = (float)(csqrt_(d2) - (double)lo);
                    v = __builtin_fmaf(fr, cv[OFF + lo + 1] - cv[OFF + lo],
                                       cv[OFF + lo]);
                }
                const float e = __expf(v);
                num[S] = __builtin_fmaf(e, Sv, num[S]);
                den[S] = __builtin_fmaf((float)mult, e, den[S]);
            } else {                             // inside patch, outside radius
                num[S] += Sv;
                den[S] += (float)mult;
            }
        }
        if constexpr (S < 6) SecAcc<M, K, S + 1>::run(cv, Sv, num, den);
    }
};

template<int M, int K>
struct RingK {
    static __device__ __forceinline__ void run(const float* cv, const float* s_f,
                                               int base, float* num, float* den) {
        const float Sv = ringsum<M, K>(s_f, base);
        SecAcc<M, K, 0>::run(cv, Sv, num, den);
        if constexpr (K < M) RingK<M, K + 1>::run(cv, s_f, base, num, den);
    }
};

template<int M>
struct RingLoop {
    static __device__ __forceinline__ void run(const float* cv, const float* s_f,
                                               int base, float* num, float* den) {
        RingK<M, 0>::run(cv, s_f, base, num, den);
        if constexpr (M < 7) RingLoop<M + 1>::run(cv, s_f, base, num, den);
    }
};

// ---------------------------------------------------------------------------
// Fused out-conv (64->35, COT=3) + KPN, all-LDS inner loop (R7 structure).
// LDS: stage 41472 (aliased by core 256x37 fp32) + frames 5760 + wgt 27648.
// w_out chunk1 = slots 1728..3455 (element 13824 onward).
// ---------------------------------------------------------------------------
__global__ __launch_bounds__(256, 2)
void conv_kpn(const ushort_t* __restrict__ in, const ushort_t* __restrict__ wp,
              const float* __restrict__ bias, const float* __restrict__ frames,
              float* __restrict__ out)
{
    __shared__ __align__(16) char smem[41472 + 5760 + 27648];
    i32x4* s4 = (i32x4*)smem;                    // stage [(r*8+oct)*18+x]
    float* s_core = (float*)smem;                // [px 256][ch 37]
    float* s_f = (float*)(smem + 41472);         // frames 30x48
    i32x4* sw = (i32x4*)(smem + 41472 + 5760);   // wgt chunk: 1728 slots

    const int tid = threadIdx.x;
    const int x0 = blockIdx.x * 16, y0 = blockIdx.y * 16, b = blockIdx.z;

    {
        i32x4 ta[11];
#pragma unroll
        for (int k = 0; k < 11; ++k) {
            const int idx = tid + k * 256;
            ta[k] = 0;
            if (idx < 2592) {
                const int oct = idx & 7, p = idx >> 3;
                const int r = p / 18, xx = p - r * 18;
                const int gy = y0 - 1 + r, gx = x0 - 1 + xx;
                if ((unsigned)gy < HH && (unsigned)gx < WW)
                    ta[k] = *(const i32x4*)(in +
                        ((size_t)((b * HH + gy) * WW + gx)) * 64 + oct * 8);
            }
        }
        float ff[4];
#pragma unroll
        for (int k = 0; k < 4; ++k) {
            const int idx = tid + k * 256;
            ff[k] = 0.f;
            if (idx < 900) {
                const int r = idx / 30, c = idx - r * 30;
                const int y = y0 - 7 + r, x = x0 - 7 + c;
                if ((unsigned)y < HH && (unsigned)x < WW)
                    ff[k] = frames[((size_t)b * HH + y) * WW + x];
            }
        }
        i32x4 tw[7];
#pragma unroll
        for (int k = 0; k < 7; ++k) {
            const int idx = tid + k * 256;
            tw[k] = 0;
            if (idx < 1728)
                tw[k] = *(const i32x4*)(wp + (size_t)idx * 8);
        }
#pragma unroll
        for (int k = 0; k < 11; ++k) {
            const int idx = tid + k * 256;
            if (idx < 2592) {
                const int oct = idx & 7, p = idx >> 3;
                const int r = p / 18, xx = p - r * 18;
                s4[(r * 8 + oct) * 18 + xx] = ta[k];
            }
        }
#pragma unroll
        for (int k = 0; k < 4; ++k) {
            const int idx = tid + k * 256;
            if (idx < 900) {
                const int r = idx / 30, c = idx - r * 30;
                s_f[r * 48 + c] = ff[k];
            }
        }
#pragma unroll
        for (int k = 0; k < 7; ++k) {
            const int idx = tid + k * 256;
            if (idx < 1728) sw[idx] = tw[k];
        }
    }
    __syncthreads();

    const int lane = tid & 63, w4 = (tid >> 6) * 4;
    const int n = lane & 15, q = lane >> 4;

    f32x4 acc[4][3];
#pragma unroll
    for (int i = 0; i < 4; ++i)
#pragma unroll
        for (int j = 0; j < 3; ++j) acc[i][j] = 0.f;

    // prefetch wgt chunk1 (slots 1728..3455)
    i32x4 pw[7];
#pragma unroll
    for (int k = 0; k < 7; ++k) {
        const int idx = tid + k * 256;
        pw[k] = 0;
        if (idx < 1728)
            pw[k] = *(const i32x4*)(wp + (size_t)(1728 + idx) * 8);
    }

    // ---- chunk 0: t-major ----
#pragma unroll
    for (int t = 0; t < 9; ++t) {
        const int ky = t / 3, kx = t - ky * 3;
        V16 bf[4];
#pragma unroll
        for (int nt = 0; nt < 4; ++nt)
            bf[nt].i4 = s4[((w4 + nt + ky) * 8 + q) * 18 + (n + kx)];
#pragma unroll
        for (int mt = 0; mt < 3; ++mt) {
            V16 af; af.i4 = sw[(t * 3 + mt) * 64 + lane];
#pragma unroll
            for (int nt = 0; nt < 4; ++nt)
                acc[nt][mt] = __builtin_amdgcn_mfma_f32_16x16x32_bf16(
                    af.v, bf[nt].v, acc[nt][mt], 0, 0, 0);
        }
    }

    __syncthreads();
#pragma unroll
    for (int k = 0; k < 7; ++k) {
        const int idx = tid + k * 256;
        if (idx < 1728) sw[idx] = pw[k];
    }
    __syncthreads();

    // ---- chunk 1 ----
#pragma unroll
    for (int t = 0; t < 9; ++t) {
        const int ky = t / 3, kx = t - ky * 3;
        V16 bf[4];
#pragma unroll
        for (int nt = 0; nt < 4; ++nt)
            bf[nt].i4 = s4[((w4 + nt + ky) * 8 + 4 + q) * 18 + (n + kx)];
#pragma unroll
        for (int mt = 0; mt < 3; ++mt) {
            V16 af; af.i4 = sw[(t * 3 + mt) * 64 + lane];
#pragma unroll
            for (int nt = 0; nt < 4; ++nt)
                acc[nt][mt] = __builtin_amdgcn_mfma_f32_16x16x32_bf16(
                    af.v, bf[nt].v, acc[nt][mt], 0, 0, 0);
        }
    }

    __syncthreads();                             // stage reads done; write core
#pragma unroll
    for (int nt = 0; nt < 4; ++nt) {
        const int px = (w4 + nt) * 16 + n;
#pragma unroll
        for (int mt = 0; mt < 3; ++mt) {
#pragma unroll
            for (int r = 0; r < 4; ++r) {
                const int ch = mt * 16 + q * 4 + r;
                if (ch < 35)
                    s_core[px * 37 + ch] = fabsf(acc[nt][mt][r] + bias[ch]);
            }
        }
    }
    __syncthreads();

    const int ty = tid >> 4, tx = tid & 15;
    const int base = (ty + 7) * 48 + (tx + 7);
    const float* cv = s_core + tid * 37;

    float num[7], den[7];
#pragma unroll
    for (int s = 0; s < 7; ++s) { num[s] = 0.f; den[s] = 0.f; }
    RingLoop<0>::run(cv, s_f, base, num, den);
    float pred = 0.f;
#pragma unroll
    for (int s = 0; s < 7; ++s) pred += num[s] / den[s];

    out[((size_t)b * HH + y0 + ty) * WW + x0 + tx] = pred;
}

// ---------------------------------------------------------------------------
extern "C" void kernel_launch(void* const* d_in, const int* in_sizes, int n_in,
                              void* d_out, int out_size, void* d_ws, size_t ws_size,
                              hipStream_t stream)
{
    const float* est     = (const float*)d_in[0];
    const float* data    = (const float*)d_in[1];
    const float* w_first = (const float*)d_in[2];
    const float* b_first = (const float*)d_in[3];
    const float* w1a = (const float*)d_in[4];
    const float* b1a = (const float*)d_in[5];
    const float* w1b = (const float*)d_in[6];
    const float* b1b = (const float*)d_in[7];
    const float* w2a = (const float*)d_in[8];
    const float* b2a = (const float*)d_in[9];
    const float* w2b = (const float*)d_in[10];
    const float* b2b = (const float*)d_in[11];
    const float* w3a = (const float*)d_in[12];
    const float* b3a = (const float*)d_in[13];
    const float* w3b = (const float*)d_in[14];
    const float* b3b = (const float*)d_in[15];
    const float* w_out = (const float*)d_in[16];
    const float* b_out = (const float*)d_in[17];

    ushort_t* X  = (ushort_t*)d_ws;                         // NHWC bf16 (B,H,W,64)
    ushort_t* T  = X + (size_t)BB * HH * WW * 64;
    ushort_t* Wd = T + (size_t)BB * HH * WW * 64;           // repacked weights

    WSrc wsrc;
    wsrc.p[0] = w1a; wsrc.p[1] = w1b; wsrc.p[2] = w2a; wsrc.p[3] = w2b;
    wsrc.p[4] = w3a; wsrc.p[5] = w3b; wsrc.p[6] = w_out; wsrc.p[7] = w_first;

    dim3 blk(256), g(WW / 16, HH / 16, BB);
    repack_k<<<980, 256, 0, stream>>>(wsrc, Wd);
    conv_first<<<g, blk, 0, stream>>>(est, Wd + 248832, b_first, X);
    conv_mfma<true,  false><<<g, blk, 0, stream>>>(X, Wd + 0,      b1a, nullptr, T);
    conv_mfma<false, true ><<<g, blk, 0, stream>>>(T, Wd + 36864,  b1b, X, X);
    conv_mfma<true,  false><<<g, blk, 0, stream>>>(X, Wd + 73728,  b2a, nullptr, T);
    conv_mfma<false, true ><<<g, blk, 0, stream>>>(T, Wd + 110592, b2b, X, X);
    conv_mfma<true,  false><<<g, blk, 0, stream>>>(X, Wd + 147456, b3a, nullptr, T);
    conv_mfma<false, true ><<<g, blk, 0, stream>>>(T, Wd + 184320, b3b, X, X);
    conv_kpn<<<g, blk, 0, stream>>>(X, Wd + 221184, b_out, data, (float*)d_out);
}